// Round 1
// 1051.451 us; speedup vs baseline: 1.2328x; 1.2328x over previous
//
#include <hip/hip_runtime.h>

#define B_SZ 16384
#define DIM  1024
#define NH   16
#define HD   64
#define FFN_ 4096

typedef __bf16 bf16x8 __attribute__((ext_vector_type(8)));
typedef unsigned short u16x8 __attribute__((ext_vector_type(8)));
typedef float f32x4 __attribute__((ext_vector_type(4)));

__device__ __forceinline__ unsigned short f2bf(float x) {
    union { float f; unsigned int u; } v; v.f = x;
    unsigned int r = v.u + 0x7FFFu + ((v.u >> 16) & 1u);
    return (unsigned short)(r >> 16);
}
__device__ __forceinline__ float bf2f(unsigned short u) {
    union { unsigned int u32; float f; } v; v.u32 = ((unsigned int)u) << 16;
    return v.f;
}

__device__ __forceinline__ void gload16(const void* g, void* lds) {
    __builtin_amdgcn_global_load_lds(
        (__attribute__((address_space(1))) void*)g,
        (__attribute__((address_space(3))) void*)lds,
        16, 0, 0);
}

// ---------------------------------------------------------------------------
// transpose + fp32->bf16 convert: W [K,N] fp32 -> WT [N,K] bf16
// ---------------------------------------------------------------------------
__global__ __launch_bounds__(256) void transpose_conv(
    const float* __restrict__ W, unsigned short* __restrict__ WT, int K, int N)
{
    __shared__ float tile[32][33];
    const int n0 = blockIdx.x * 32, k0 = blockIdx.y * 32;
    const int tx = threadIdx.x, ty = threadIdx.y;
    #pragma unroll
    for (int i = ty; i < 32; i += 8)
        tile[i][tx] = W[(size_t)(k0 + i) * N + n0 + tx];
    __syncthreads();
    #pragma unroll
    for (int i = ty; i < 32; i += 8)
        WT[(size_t)(n0 + i) * K + k0 + tx] = f2bf(tile[tx][i]);
}

__global__ __launch_bounds__(256) void concat_bias(
    const float* __restrict__ bk, const float* __restrict__ bv,
    float* __restrict__ bkv)
{
    int i = blockIdx.x * 256 + threadIdx.x;
    if (i < 1024) { bkv[i] = bk[i]; bkv[1024 + i] = bv[i]; }
}

// savg = bf16(mean(m0,m1,m2)); optionally also bf16 copies of m0,m1,m2
// (mjb = [3][B][DIM] bf16, j-major) for the bf16 KV GEMM path.
__global__ __launch_bounds__(256) void conv_inputs(
    const float4* __restrict__ m0, const float4* __restrict__ m1,
    const float4* __restrict__ m2, ushort4* __restrict__ savg,
    ushort4* __restrict__ mjb, int n4)
{
    int idx = blockIdx.x * blockDim.x + threadIdx.x;
    int stride = gridDim.x * blockDim.x;
    const float k = 1.f / 3.f;
    for (int i = idx; i < n4; i += stride) {
        float4 a = m0[i], b = m1[i], c = m2[i];
        ushort4 us;
        us.x = f2bf((a.x + b.x + c.x) * k); us.y = f2bf((a.y + b.y + c.y) * k);
        us.z = f2bf((a.z + b.z + c.z) * k); us.w = f2bf((a.w + b.w + c.w) * k);
        savg[i] = us;
        if (mjb) {
            ushort4 ua, ub, uc;
            ua.x = f2bf(a.x); ua.y = f2bf(a.y); ua.z = f2bf(a.z); ua.w = f2bf(a.w);
            ub.x = f2bf(b.x); ub.y = f2bf(b.y); ub.z = f2bf(b.z); ub.w = f2bf(b.w);
            uc.x = f2bf(c.x); uc.y = f2bf(c.y); uc.z = f2bf(c.z); uc.w = f2bf(c.w);
            mjb[i] = ua; mjb[n4 + i] = ub; mjb[2 * n4 + i] = uc;
        }
    }
}

// ---------------------------------------------------------------------------
// LEGACY 128x128 GEMM (kept for fallback tiers / AF32 KV path).
// ---------------------------------------------------------------------------
template <int MODE, bool AF32>
__global__ __launch_bounds__(256) void gemm2(
    const unsigned short* __restrict__ A,
    const float* __restrict__ A0, const float* __restrict__ A1,
    const float* __restrict__ A2, int chunk0, int Bc,
    const unsigned short* __restrict__ BT,
    const float* __restrict__ bias,
    const void* __restrict__ res,
    void* __restrict__ out, int K, int N)
{
    __shared__ __align__(16) char AsRaw[AF32 ? 32768 : 16384];
    __shared__ __align__(16) unsigned short Bs[2][4096];

    const int tid  = threadIdx.x;
    const int lane = tid & 63;
    const int wave = tid >> 6;
    const int wm = (wave >> 1) * 64;
    const int wn = (wave & 1) * 64;
    const int lr = lane & 15;
    const int quad = lane >> 4;

    const size_t rowB = (size_t)blockIdx.y * 128 + (tid >> 2);
    const int kcolB = (tid & 3) * 8;
    const unsigned short* Bg = BT + rowB * K + kcolB;

    const unsigned short* Ag = nullptr;
    const float* Agf = nullptr;
    if constexpr (AF32) {
        const int grow = blockIdx.x * 128;
        const int j = grow / Bc;
        const int b0 = (grow - j * Bc) + chunk0;
        const float* msrc = (j == 0) ? A0 : (j == 1) ? A1 : A2;
        const int arow = tid >> 3;
        const int jj = (tid & 7) ^ (arow & 7);
        Agf = msrc + (size_t)(b0 + arow) * DIM + jj * 4;
    } else {
        const size_t rowA = (size_t)blockIdx.x * 128 + (tid >> 2);
        Ag = A + rowA * K + kcolB;
    }

    f32x4 zero = {0.f, 0.f, 0.f, 0.f};
    f32x4 acc[4][4];
    #pragma unroll
    for (int i = 0; i < 4; ++i)
        #pragma unroll
        for (int j = 0; j < 4; ++j) acc[i][j] = zero;

    for (int k0 = 0; k0 < K; k0 += 64) {
        if constexpr (AF32) {
            float* Asf = (float*)AsRaw;
            #pragma unroll
            for (int h = 0; h < 2; ++h) {
                #pragma unroll
                for (int i = 0; i < 4; ++i)
                    gload16(Agf + (size_t)i * 32 * DIM + k0 + 32 * h,
                            (char*)(Asf + h * 4096) + i * 4096 + tid * 16);
            }
        } else {
            unsigned short* As = (unsigned short*)AsRaw;
            gload16(Ag + k0,                 (char*)As + tid * 16);
            gload16(Ag + (size_t)64 * K + k0,(char*)As + 4096 + tid * 16);
            gload16(Ag + k0 + 32,            (char*)As + 8192 + tid * 16);
            gload16(Ag + (size_t)64 * K + k0 + 32,
                                             (char*)As + 12288 + tid * 16);
        }
        gload16(Bg + k0,                  (char*)Bs[0] + tid * 16);
        gload16(Bg + (size_t)64 * K + k0, (char*)Bs[0] + 4096 + tid * 16);
        gload16(Bg + k0 + 32,             (char*)Bs[1] + tid * 16);
        gload16(Bg + (size_t)64 * K + k0 + 32,
                                          (char*)Bs[1] + 4096 + tid * 16);
        __syncthreads();

        #pragma unroll
        for (int h = 0; h < 2; ++h) {
            u16x8 af[4], bfr[4];
            if constexpr (AF32) {
                const float* Asf = (const float*)AsRaw + h * 4096;
                #pragma unroll
                for (int mi = 0; mi < 4; ++mi) {
                    const int r = wm + mi * 16 + lr;
                    const int s = lr & 7;
                    const float* rp = Asf + r * 32;
                    union { f32x4 f; unsigned int u[4]; } a0, a1;
                    a0.f = *(const f32x4*)(rp + (((quad << 1) ^ s) << 2));
                    a1.f = *(const f32x4*)(rp + ((((quad << 1) | 1) ^ s) << 2));
                    union { unsigned int i[4]; u16x8 v; } pk;
                    pk.i[0] = __builtin_amdgcn_perm(a0.u[1], a0.u[0], 0x07060302);
                    pk.i[1] = __builtin_amdgcn_perm(a0.u[3], a0.u[2], 0x07060302);
                    pk.i[2] = __builtin_amdgcn_perm(a1.u[1], a1.u[0], 0x07060302);
                    pk.i[3] = __builtin_amdgcn_perm(a1.u[3], a1.u[2], 0x07060302);
                    af[mi] = pk.v;
                }
            } else {
                const unsigned short* As =
                    (const unsigned short*)AsRaw + h * 4096;
                #pragma unroll
                for (int mi = 0; mi < 4; ++mi)
                    af[mi] = *(const u16x8*)&As[(wm + mi * 16 + lr) * 32 + quad * 8];
            }
            #pragma unroll
            for (int nj = 0; nj < 4; ++nj)
                bfr[nj] = *(const u16x8*)&Bs[h][(wn + nj * 16 + lr) * 32 + quad * 8];

            #pragma unroll
            for (int mi = 0; mi < 4; ++mi)
                #pragma unroll
                for (int nj = 0; nj < 4; ++nj)
                    acc[mi][nj] = __builtin_amdgcn_mfma_f32_16x16x32_bf16(
                        __builtin_bit_cast(bf16x8, af[mi]),
                        __builtin_bit_cast(bf16x8, bfr[nj]),
                        acc[mi][nj], 0, 0, 0);
        }
        __syncthreads();
    }

    const size_t rbase = (size_t)blockIdx.x * 128 + wm + quad * 4;
    const int cbase = blockIdx.y * 128 + wn + lr;
    #pragma unroll
    for (int mi = 0; mi < 4; ++mi) {
        #pragma unroll
        for (int nj = 0; nj < 4; ++nj) {
            const int gc = cbase + nj * 16;
            const float bv = bias[gc];
            #pragma unroll
            for (int r = 0; r < 4; ++r) {
                const size_t gr = rbase + mi * 16 + r;
                float v = acc[mi][nj][r] + bv;
                if (MODE == 1) v += ((const float*)res)[gr * N + gc];
                if (MODE == 2) v = v > 0.f ? v : 0.f;
                if (MODE == 4) {
                    v += bf2f(((const unsigned short*)res)[gr * N + gc]);
                    ((float*)out)[gr * N + gc] = v;
                } else {
                    ((unsigned short*)out)[gr * N + gc] = f2bf(v);
                }
            }
        }
    }
}

// ---------------------------------------------------------------------------
// 256x256x(BK=64) 8-wave pipelined GEMM: C[M,N] = A[M,K] @ BT[N,K]^T (+bias).
// 8 waves as 2(M)x4(N); per-wave output 2x(64 rows) x 2x(32 cols) via 4
// quadrant phases per K-tile. LDS: 2 double-buffers x (A 2x16KB + B 2x16KB)
// = 128 KiB dynamic. Staging via global_load_lds w/ counted vmcnt(4) per
// phase (never 0 in steady state); raw s_barrier (no waitcnt drain);
// setprio(1) around MFMA clusters. LDS XOR swizzle (byte ^= (row&7)<<4)
// realized by pre-swizzling the GLOBAL source column (gload_lds writes
// linearly) and applying the same XOR on the ds_read address ->
// conflict-free stride-128B fragment reads.
// vmcnt ledger (stage order per tile t -> buf^1: [A0,B0,B1,A1], 2 loads ea):
//   prologue: A0,B0,B1,A1 of t0; vmcnt(4) -> A0,B0 landed.
//   ph0 stage A0' vm(4)->B1 landed; ph1 stage B0' vm(4)->A1 landed;
//   ph2 stage B1' vm(4)->A0' landed; ph3 stage A1' vm(4)->B0' landed.
//   Every half lands >=1 barrier before its first read. Last tile: 2 -> 0.
// MODE 0: bf16 = acc+bias ; 1: bf16 = acc+bias+f32 res ; 2: bf16 relu ;
// 4: f32 = acc+bias+bf16 res.  CH: A rows = [3][B_SZ] j-major chunk mapping.
// ---------------------------------------------------------------------------
template <int MODE, bool CH>
__global__ __launch_bounds__(512, 2) void gemm256(
    const unsigned short* __restrict__ A, int chunk0, int Bc,
    const unsigned short* __restrict__ BT,
    const float* __restrict__ bias,
    const void* __restrict__ res,
    void* __restrict__ out, int K, int N)
{
    extern __shared__ __align__(16) char smem[];
    const int tid  = threadIdx.x;
    const int lane = tid & 63;
    const int wave = tid >> 6;
    const int wm = wave >> 2;       // 0..1
    const int wn = wave & 3;        // 0..3
    const int lr = lane & 15;
    const int quad = lane >> 4;

    // staging mapping: per half-tile, thread covers LDS bytes
    // {tid*16, 8192+tid*16}; source col-byte pre-swizzled.
    const int srow  = tid >> 3;                           // 0..63 (+64 for i=1)
    const int scolb = ((tid & 7) ^ (srow & 7)) << 4;      // swizzled src col

    size_t arow0;
    if constexpr (CH) {
        const int grow = blockIdx.x * 256;
        const int j = grow / Bc;
        arow0 = (size_t)j * B_SZ + chunk0 + (grow - j * Bc);
    } else {
        arow0 = (size_t)blockIdx.x * 256;
    }
    const unsigned short* Ag = A + (arow0 + srow) * (size_t)K + (scolb >> 1);
    const unsigned short* Bg =
        BT + ((size_t)blockIdx.y * 256 + srow) * (size_t)K + (scolb >> 1);
    char* lds0 = smem + tid * 16;

    // fragment-read swizzled column bytes (row&7 == lr&7 for all our rows)
    const int cbx0 = (quad * 16) ^ ((lr & 7) << 4);
    const int cbx1 = (64 + quad * 16) ^ ((lr & 7) << 4);

    f32x4 zero = {0.f, 0.f, 0.f, 0.f};
    f32x4 acc[2][2][4][2];
    #pragma unroll
    for (int a = 0; a < 2; ++a)
        #pragma unroll
        for (int b = 0; b < 2; ++b)
            #pragma unroll
            for (int c = 0; c < 4; ++c)
                #pragma unroll
                for (int d = 0; d < 2; ++d) acc[a][b][c][d] = zero;

    u16x8 af[4][2], bf0[2][2], bf1[2][2];

#define STAGE_A(nb, m, t) do {                                          \
        const unsigned short* s_ = Ag + (size_t)((m) * 128) * K + (t) * 64; \
        char* d_ = lds0 + (nb) * 65536 + (m) * 16384;                   \
        gload16(s_, d_);                                                \
        gload16(s_ + (size_t)64 * K, d_ + 8192); } while (0)
#define STAGE_B(nb, n, t) do {                                          \
        const unsigned short* s_ = Bg + (size_t)((n) * 128) * K + (t) * 64; \
        char* d_ = lds0 + (nb) * 65536 + 32768 + (n) * 16384;           \
        gload16(s_, d_);                                                \
        gload16(s_ + (size_t)64 * K, d_ + 8192); } while (0)
#define LOADA(nb, hm) do {                                              \
        const char* b_ = smem + (nb) * 65536 + (hm) * 16384;            \
        _Pragma("unroll")                                               \
        for (int mi = 0; mi < 4; ++mi) {                                \
            const int ar_ = wm * 64 + mi * 16 + lr;                     \
            af[mi][0] = *(const u16x8*)(b_ + ar_ * 128 + cbx0);         \
            af[mi][1] = *(const u16x8*)(b_ + ar_ * 128 + cbx1); } } while (0)
#define LOADB(nb, hn, dst) do {                                         \
        const char* b_ = smem + (nb) * 65536 + 32768 + (hn) * 16384;    \
        _Pragma("unroll")                                               \
        for (int nj = 0; nj < 2; ++nj) {                                \
            const int br_ = wn * 32 + nj * 16 + lr;                     \
            dst[nj][0] = *(const u16x8*)(b_ + br_ * 128 + cbx0);        \
            dst[nj][1] = *(const u16x8*)(b_ + br_ * 128 + cbx1); } } while (0)
#define MFMAQ(QM, QN, BF)                                               \
        _Pragma("unroll")                                               \
        for (int mi = 0; mi < 4; ++mi)                                  \
        _Pragma("unroll")                                               \
        for (int nj = 0; nj < 2; ++nj)                                  \
        _Pragma("unroll")                                               \
        for (int ks = 0; ks < 2; ++ks)                                  \
            acc[QM][QN][mi][nj] = __builtin_amdgcn_mfma_f32_16x16x32_bf16( \
                __builtin_bit_cast(bf16x8, af[mi][ks]),                 \
                __builtin_bit_cast(bf16x8, BF[nj][ks]),                 \
                acc[QM][QN][mi][nj], 0, 0, 0);

    const int NT = K >> 6;
    STAGE_A(0, 0, 0); STAGE_B(0, 0, 0); STAGE_B(0, 1, 0); STAGE_A(0, 1, 0);
    asm volatile("s_waitcnt vmcnt(4)" ::: "memory");
    __builtin_amdgcn_s_barrier();

    for (int t = 0; t < NT; ++t) {
        const int nb = t & 1, ob = nb ^ 1;
        const bool more = (t + 1) < NT;
        // phase 0: quadrant (0,0)
        LOADA(nb, 0); LOADB(nb, 0, bf0);
        if (more) { STAGE_A(ob, 0, t + 1);
                    asm volatile("s_waitcnt vmcnt(4)" ::: "memory"); }
        else      { asm volatile("s_waitcnt vmcnt(2)" ::: "memory"); }
        __builtin_amdgcn_s_barrier();
        __builtin_amdgcn_s_setprio(1);
        MFMAQ(0, 0, bf0);
        __builtin_amdgcn_s_setprio(0);
        __builtin_amdgcn_s_barrier();
        // phase 1: quadrant (0,1)
        LOADB(nb, 1, bf1);
        if (more) { STAGE_B(ob, 0, t + 1);
                    asm volatile("s_waitcnt vmcnt(4)" ::: "memory"); }
        else      { asm volatile("s_waitcnt vmcnt(0)" ::: "memory"); }
        __builtin_amdgcn_s_barrier();
        __builtin_amdgcn_s_setprio(1);
        MFMAQ(0, 1, bf1);
        __builtin_amdgcn_s_setprio(0);
        __builtin_amdgcn_s_barrier();
        // phase 2: quadrant (1,1)
        LOADA(nb, 1);
        if (more) { STAGE_B(ob, 1, t + 1);
                    asm volatile("s_waitcnt vmcnt(4)" ::: "memory"); }
        __builtin_amdgcn_s_barrier();
        __builtin_amdgcn_s_setprio(1);
        MFMAQ(1, 1, bf1);
        __builtin_amdgcn_s_setprio(0);
        __builtin_amdgcn_s_barrier();
        // phase 3: quadrant (1,0)  (bf0 still live from phase 0)
        if (more) { STAGE_A(ob, 1, t + 1);
                    asm volatile("s_waitcnt vmcnt(4)" ::: "memory"); }
        __builtin_amdgcn_s_barrier();
        __builtin_amdgcn_s_setprio(1);
        MFMAQ(1, 0, bf0);
        __builtin_amdgcn_s_setprio(0);
        __builtin_amdgcn_s_barrier();
    }

#undef STAGE_A
#undef STAGE_B
#undef LOADA
#undef LOADB
#undef MFMAQ

    // epilogue: C/D layout col = lane&15, row = quad*4 + reg
    #pragma unroll
    for (int qm = 0; qm < 2; ++qm) {
        #pragma unroll
        for (int qn = 0; qn < 2; ++qn) {
            #pragma unroll
            for (int mi = 0; mi < 4; ++mi) {
                #pragma unroll
                for (int nj = 0; nj < 2; ++nj) {
                    const size_t gr0 = (size_t)blockIdx.x * 256 + qm * 128 +
                                       wm * 64 + mi * 16 + quad * 4;
                    const int gc = blockIdx.y * 256 + qn * 128 + wn * 32 +
                                   nj * 16 + lr;
                    const float bv = bias[gc];
                    f32x4 av = acc[qm][qn][mi][nj];
                    #pragma unroll
                    for (int r = 0; r < 4; ++r) {
                        const size_t gr = gr0 + r;
                        float v = av[r] + bv;
                        if (MODE == 1) v += ((const float*)res)[gr * N + gc];
                        if (MODE == 2) v = v > 0.f ? v : 0.f;
                        if (MODE == 4) {
                            v += bf2f(((const unsigned short*)res)[gr * N + gc]);
                            ((float*)out)[gr * N + gc] = v;
                        } else {
                            ((unsigned short*)out)[gr * N + gc] = f2bf(v);
                        }
                    }
                }
            }
        }
    }
}

// ---------------------------------------------------------------------------
// attention (3 keys) + residual + LN1.  One row per block, 256 threads.
// ---------------------------------------------------------------------------
__global__ __launch_bounds__(256) void attn_ln1(
    const unsigned short* __restrict__ qb,
    const unsigned short* __restrict__ KVb,
    const float* __restrict__ domain,
    const float* __restrict__ g1, const float* __restrict__ beta1,
    unsigned short* __restrict__ x1b, int chunk0, int Bc)
{
    const int b = blockIdx.x;
    const int t = threadIdx.x;
    const int d0 = t * 4;
    const size_t gbase = (size_t)(chunk0 + b) * DIM + d0;

    float q[4];
    { ushort4 u = *(const ushort4*)(qb + gbase);
      q[0] = bf2f(u.x); q[1] = bf2f(u.y); q[2] = bf2f(u.z); q[3] = bf2f(u.w); }

    float vv[3][4], s[3];
    #pragma unroll
    for (int j = 0; j < 3; ++j) {
        const size_t off = ((size_t)j * Bc + b) * 2048 + d0;
        ushort4 ku = *(const ushort4*)(KVb + off);
        ushort4 vu = *(const ushort4*)(KVb + off + 1024);
        float p = q[0] * bf2f(ku.x) + q[1] * bf2f(ku.y) +
                  q[2] * bf2f(ku.z) + q[3] * bf2f(ku.w);
        vv[j][0] = bf2f(vu.x); vv[j][1] = bf2f(vu.y);
        vv[j][2] = bf2f(vu.z); vv[j][3] = bf2f(vu.w);
        p += __shfl_down(p, 8, 16);
        p += __shfl_down(p, 4, 16);
        p += __shfl_down(p, 2, 16);
        p += __shfl_down(p, 1, 16);
        p = __shfl(p, 0, 16);
        s[j] = p * 0.125f;
    }
    float mx = fmaxf(s[0], fmaxf(s[1], s[2]));
    float e0 = __expf(s[0] - mx), e1 = __expf(s[1] - mx), e2 = __expf(s[2] - mx);
    float inv = 1.f / (e0 + e1 + e2);
    float a0 = e0 * inv, a1 = e1 * inv, a2 = e2 * inv;

    float4 dm = *(const float4*)(domain + gbase);
    float y[4];
    y[0] = dm.x + a0 * vv[0][0] + a1 * vv[1][0] + a2 * vv[2][0];
    y[1] = dm.y + a0 * vv[0][1] + a1 * vv[1][1] + a2 * vv[2][1];
    y[2] = dm.z + a0 * vv[0][2] + a1 * vv[1][2] + a2 * vv[2][2];
    y[3] = dm.w + a0 * vv[0][3] + a1 * vv[1][3] + a2 * vv[2][3];

    float sum = y[0] + y[1] + y[2] + y[3];
    float sq  = y[0]*y[0] + y[1]*y[1] + y[2]*y[2] + y[3]*y[3];
    #pragma unroll
    for (int off = 32; off > 0; off >>= 1) {
        sum += __shfl_down(sum, off, 64);
        sq  += __shfl_down(sq,  off, 64);
    }
    __shared__ float red[8];
    const int wv = t >> 6, ln = t & 63;
    if (ln == 0) { red[wv] = sum; red[4 + wv] = sq; }
    __syncthreads();
    float tot = red[0] + red[1] + red[2] + red[3];
    float tsq = red[4] + red[5] + red[6] + red[7];
    float mu = tot * (1.f / DIM);
    float var = tsq * (1.f / DIM) - mu * mu;
    float rs = rsqrtf(var + 1e-5f);
    #pragma unroll
    for (int i = 0; i < 4; ++i) {
        int d = d0 + i;
        float xv = (y[i] - mu) * rs * g1[d] + beta1[d];
        x1b[gbase + i] = f2bf(xv);
    }
}

// ---------------------------------------------------------------------------
// LN2 + [DIM,3] projection + softmax.  One row per block, 256 threads.
// ---------------------------------------------------------------------------
__global__ __launch_bounds__(256) void ln2_proj(
    const float* __restrict__ xr,
    const float* __restrict__ g2, const float* __restrict__ beta2,
    const float* __restrict__ Ww, const float* __restrict__ bw,
    float* __restrict__ out, int chunk0)
{
    const int b = blockIdx.x;
    const int t = threadIdx.x;
    const int d0 = t * 4;
    const size_t base = (size_t)b * DIM + d0;
    float4 x = *(const float4*)(xr + base);
    float xs[4] = {x.x, x.y, x.z, x.w};

    float sum = xs[0] + xs[1] + xs[2] + xs[3];
    float sq  = xs[0]*xs[0] + xs[1]*xs[1] + xs[2]*xs[2] + xs[3]*xs[3];
    #pragma unroll
    for (int off = 32; off > 0; off >>= 1) {
        sum += __shfl_down(sum, off, 64);
        sq  += __shfl_down(sq,  off, 64);
    }
    __shared__ float red[8];
    const int wv = t >> 6, ln = t & 63;
    if (ln == 0) { red[wv] = sum; red[4 + wv] = sq; }
    __syncthreads();
    float tot = red[0] + red[1] + red[2] + red[3];
    float tsq = red[4] + red[5] + red[6] + red[7];
    float mu = tot * (1.f / DIM);
    float var = tsq * (1.f / DIM) - mu * mu;
    float rs = rsqrtf(var + 1e-5f);

    float p0 = 0.f, p1 = 0.f, p2 = 0.f;
    #pragma unroll
    for (int i = 0; i < 4; ++i) {
        int d = d0 + i;
        float xv = (xs[i] - mu) * rs * g2[d] + beta2[d];
        p0 += xv * Ww[d * 3 + 0];
        p1 += xv * Ww[d * 3 + 1];
        p2 += xv * Ww[d * 3 + 2];
    }
    #pragma unroll
    for (int off = 32; off > 0; off >>= 1) {
        p0 += __shfl_down(p0, off, 64);
        p1 += __shfl_down(p1, off, 64);
        p2 += __shfl_down(p2, off, 64);
    }
    __shared__ float pr[12];
    if (ln == 0) { pr[wv] = p0; pr[4 + wv] = p1; pr[8 + wv] = p2; }
    __syncthreads();
    if (t == 0) {
        float l0 = pr[0] + pr[1] + pr[2] + pr[3] + bw[0];
        float l1 = pr[4] + pr[5] + pr[6] + pr[7] + bw[1];
        float l2 = pr[8] + pr[9] + pr[10] + pr[11] + bw[2];
        float m = fmaxf(l0, fmaxf(l1, l2));
        float e0 = __expf(l0 - m), e1 = __expf(l1 - m), e2 = __expf(l2 - m);
        float inv = 1.f / (e0 + e1 + e2);
        out[(size_t)(chunk0 + b) * 3 + 0] = e0 * inv;
        out[(size_t)(chunk0 + b) * 3 + 1] = e1 * inv;
        out[(size_t)(chunk0 + b) * 3 + 2] = e2 * inv;
    }
}

// ---------------------------------------------------------------------------
extern "C" void kernel_launch(void* const* d_in, const int* in_sizes, int n_in,
                              void* d_out, int out_size, void* d_ws, size_t ws_size,
                              hipStream_t stream)
{
    const float* m0     = (const float*)d_in[0];
    const float* m1     = (const float*)d_in[1];
    const float* m2     = (const float*)d_in[2];
    const float* domain = (const float*)d_in[3];
    const float* Wg = (const float*)d_in[4];  const float* bg = (const float*)d_in[5];
    const float* Wq = (const float*)d_in[6];  const float* bq = (const float*)d_in[7];
    const float* Wk = (const float*)d_in[8];  const float* bk = (const float*)d_in[9];
    const float* Wv = (const float*)d_in[10]; const float* bv = (const float*)d_in[11];
    const float* W1 = (const float*)d_in[12]; const float* b1 = (const float*)d_in[13];
    const float* W2 = (const float*)d_in[14]; const float* b2 = (const float*)d_in[15];
    const float* g1 = (const float*)d_in[16]; const float* beta1 = (const float*)d_in[17];
    const float* g2 = (const float*)d_in[18]; const float* beta2 = (const float*)d_in[19];
    const float* Ww = (const float*)d_in[20]; const float* bw = (const float*)d_in[21];
    float* out = (float*)d_out;

    char* ws = (char*)d_ws;
    const size_t MiB = 1ull << 20;

    // one-time: raise dynamic-LDS cap for gemm256 instantiations (128 KiB)
    static int attr_ok = -1;
    if (attr_ok < 0) {
        hipError_t e = hipFuncSetAttribute(
            reinterpret_cast<const void*>(&gemm256<0, false>),
            hipFuncAttributeMaxDynamicSharedMemorySize, 131072);
        if (e == hipSuccess) e = hipFuncSetAttribute(
            reinterpret_cast<const void*>(&gemm256<0, true>),
            hipFuncAttributeMaxDynamicSharedMemorySize, 131072);
        if (e == hipSuccess) e = hipFuncSetAttribute(
            reinterpret_cast<const void*>(&gemm256<1, false>),
            hipFuncAttributeMaxDynamicSharedMemorySize, 131072);
        if (e == hipSuccess) e = hipFuncSetAttribute(
            reinterpret_cast<const void*>(&gemm256<2, false>),
            hipFuncAttributeMaxDynamicSharedMemorySize, 131072);
        if (e == hipSuccess) e = hipFuncSetAttribute(
            reinterpret_cast<const void*>(&gemm256<4, false>),
            hipFuncAttributeMaxDynamicSharedMemorySize, 131072);
        attr_ok = (e == hipSuccess) ? 1 : 0;
    }

    unsigned short* wgT  = (unsigned short*)(ws);
    unsigned short* wqT  = (unsigned short*)(ws + 2 * MiB);
    unsigned short* wkvT = (unsigned short*)(ws + 4 * MiB);   // [2048,1024]
    unsigned short* w1T  = (unsigned short*)(ws + 8 * MiB);
    unsigned short* w2T  = (unsigned short*)(ws + 16 * MiB);
    float*          bkv  = (float*)(ws + 24 * MiB);

    const dim3 tb(32, 8);
    transpose_conv<<<dim3(DIM / 32, DIM / 32), tb, 0, stream>>>(Wg, wgT, DIM, DIM);
    transpose_conv<<<dim3(DIM / 32, DIM / 32), tb, 0, stream>>>(Wq, wqT, DIM, DIM);
    transpose_conv<<<dim3(DIM / 32, DIM / 32), tb, 0, stream>>>(Wk, wkvT, DIM, DIM);
    transpose_conv<<<dim3(DIM / 32, DIM / 32), tb, 0, stream>>>(
        Wv, wkvT + (size_t)DIM * DIM, DIM, DIM);
    transpose_conv<<<dim3(FFN_ / 32, DIM / 32), tb, 0, stream>>>(W1, w1T, DIM, FFN_);
    transpose_conv<<<dim3(DIM / 32, FFN_ / 32), tb, 0, stream>>>(W2, w2T, FFN_, DIM);
    concat_bias<<<4, 256, 0, stream>>>(bk, bv, bkv);

    char* base = ws + 25 * MiB;
    const int n4 = B_SZ * DIM / 4;

    if (attr_ok) {
        const bool FULLT = ws_size >= 282 * MiB;
        const bool MIDT  = !FULLT && ws_size >= 250 * MiB;
        if (FULLT || MIDT) {
            // layout: mjb 96 | qb 32 | x1b 32 | shared (savg+dq / KVb / h1+xr)
            const int BcKV = FULLT ? 8192 : 4096;
            const int BcF  = FULLT ? 8192 : 4096;
            unsigned short* mjb  = (unsigned short*)(base);
            unsigned short* qb   = (unsigned short*)(base + 96 * MiB);
            unsigned short* x1b  = (unsigned short*)(base + 128 * MiB);
            char* shared         = base + 160 * MiB;
            unsigned short* savg = (unsigned short*)(shared);
            unsigned short* dq   = (unsigned short*)(shared + 32 * MiB);
            unsigned short* KVb  = (unsigned short*)(shared);
            unsigned short* h1   = (unsigned short*)(shared);
            float*          xr   = (float*)(shared + (size_t)BcF * FFN_ * 2);

            conv_inputs<<<8192, 256, 0, stream>>>(
                (const float4*)m0, (const float4*)m1, (const float4*)m2,
                (ushort4*)savg, (ushort4*)mjb, n4);

            gemm256<1, false><<<dim3(B_SZ / 256, DIM / 256), 512, 131072, stream>>>(
                savg, 0, 0, wgT, bg, domain, dq, DIM, DIM);
            gemm256<0, false><<<dim3(B_SZ / 256, DIM / 256), 512, 131072, stream>>>(
                dq, 0, 0, wqT, bq, nullptr, qb, DIM, DIM);

            for (int c = 0; c < B_SZ / BcKV; ++c) {
                const int chunk0 = c * BcKV;
                gemm256<0, true><<<dim3(3 * BcKV / 256, 2048 / 256), 512, 131072, stream>>>(
                    mjb, chunk0, BcKV, wkvT, bkv, nullptr, KVb, DIM, 2048);
                attn_ln1<<<BcKV, 256, 0, stream>>>(qb, KVb, domain, g1, beta1,
                                                   x1b, chunk0, BcKV);
            }
            for (int c = 0; c < B_SZ / BcF; ++c) {
                const int chunk0 = c * BcF;
                const unsigned short* x1c = x1b + (size_t)chunk0 * DIM;
                gemm256<2, false><<<dim3(BcF / 256, FFN_ / 256), 512, 131072, stream>>>(
                    x1c, 0, 0, w1T, b1, nullptr, h1, DIM, FFN_);
                gemm256<4, false><<<dim3(BcF / 256, DIM / 256), 512, 131072, stream>>>(
                    h1, 0, 0, w2T, b2, x1c, xr, FFN_, DIM);
                ln2_proj<<<BcF, 256, 0, stream>>>(xr, g2, beta2, Ww, bw, out, chunk0);
            }
            return;
        }
        // fallback-KV tier: gemm256 for dq/qb/FFN, legacy AF32 gemm2 for KV
        const bool T2 = ws_size >= 185 * MiB;
        const int BcKV = T2 ? 8192 : 4096;
        const int BcF  = T2 ? 8192 : 4096;
        unsigned short* savg = (unsigned short*)(base);
        unsigned short* qb   = (unsigned short*)(base);
        unsigned short* x1b  = (unsigned short*)(base + 32 * MiB);
        unsigned short* dq   = (unsigned short*)(base + 64 * MiB);
        unsigned short* KVb  = (unsigned short*)(base + 64 * MiB);
        unsigned short* h1   = (unsigned short*)(base + 64 * MiB);
        float*          xr   = (float*)(base + 64 * MiB + (size_t)BcF * FFN_ * 2);

        conv_inputs<<<8192, 256, 0, stream>>>(
            (const float4*)m0, (const float4*)m1, (const float4*)m2,
            (ushort4*)savg, nullptr, n4);

        gemm256<1, false><<<dim3(B_SZ / 256, DIM / 256), 512, 131072, stream>>>(
            savg, 0, 0, wgT, bg, domain, dq, DIM, DIM);
        gemm256<0, false><<<dim3(B_SZ / 256, DIM / 256), 512, 131072, stream>>>(
            dq, 0, 0, wqT, bq, nullptr, qb, DIM, DIM);

        for (int c = 0; c < B_SZ / BcKV; ++c) {
            const int chunk0 = c * BcKV;
            gemm2<0, true><<<dim3(3 * BcKV / 128, 2048 / 128), 256, 0, stream>>>(
                nullptr, m0, m1, m2, chunk0, BcKV, wkvT, bkv, nullptr, KVb,
                DIM, 2048);
            attn_ln1<<<BcKV, 256, 0, stream>>>(qb, KVb, domain, g1, beta1,
                                               x1b, chunk0, BcKV);
        }
        for (int c = 0; c < B_SZ / BcF; ++c) {
            const int chunk0 = c * BcF;
            const unsigned short* x1c = x1b + (size_t)chunk0 * DIM;
            gemm256<2, false><<<dim3(BcF / 256, FFN_ / 256), 512, 131072, stream>>>(
                x1c, 0, 0, w1T, b1, nullptr, h1, DIM, FFN_);
            gemm256<4, false><<<dim3(BcF / 256, DIM / 256), 512, 131072, stream>>>(
                h1, 0, 0, w2T, b2, x1c, xr, FFN_, DIM);
            ln2_proj<<<BcF, 256, 0, stream>>>(xr, g2, beta2, Ww, bw, out, chunk0);
        }
        return;
    }

    // full legacy path (attribute raise failed): original kernel set
    {
        const bool T2 = ws_size >= 185 * MiB;
        const int BcKV = T2 ? 8192 : 4096;
        const int BcF  = T2 ? 8192 : 4096;
        unsigned short* savg = (unsigned short*)(base);
        unsigned short* qb   = (unsigned short*)(base);
        unsigned short* x1b  = (unsigned short*)(base + 32 * MiB);
        unsigned short* dq   = (unsigned short*)(base + 64 * MiB);
        unsigned short* KVb  = (unsigned short*)(base + 64 * MiB);
        unsigned short* h1   = (unsigned short*)(base + 64 * MiB);
        float*          xr   = (float*)(base + 64 * MiB + (size_t)BcF * FFN_ * 2);

        conv_inputs<<<8192, 256, 0, stream>>>(
            (const float4*)m0, (const float4*)m1, (const float4*)m2,
            (ushort4*)savg, nullptr, n4);

        gemm2<1, false><<<dim3(B_SZ / 128, DIM / 128), 256, 0, stream>>>(
            savg, nullptr, nullptr, nullptr, 0, 0, wgT, bg, domain, dq, DIM, DIM);
        gemm2<0, false><<<dim3(B_SZ / 128, DIM / 128), 256, 0, stream>>>(
            dq, nullptr, nullptr, nullptr, 0, 0, wqT, bq, nullptr, qb, DIM, DIM);

        for (int c = 0; c < B_SZ / BcKV; ++c) {
            const int chunk0 = c * BcKV;
            gemm2<0, true><<<dim3(3 * BcKV / 128, 2048 / 128), 256, 0, stream>>>(
                nullptr, m0, m1, m2, chunk0, BcKV, wkvT, bkv, nullptr, KVb,
                DIM, 2048);
            attn_ln1<<<BcKV, 256, 0, stream>>>(qb, KVb, domain, g1, beta1,
                                               x1b, chunk0, BcKV);
        }
        for (int c = 0; c < B_SZ / BcF; ++c) {
            const int chunk0 = c * BcF;
            const unsigned short* x1c = x1b + (size_t)chunk0 * DIM;
            gemm2<2, false><<<dim3(BcF / 128, FFN_ / 128), 256, 0, stream>>>(
                x1c, nullptr, nullptr, nullptr, 0, 0, w1T, b1, nullptr, h1,
                DIM, FFN_);
            gemm2<4, false><<<dim3(BcF / 128, DIM / 128), 256, 0, stream>>>(
                h1, nullptr, nullptr, nullptr, 0, 0, w2T, b2, x1c, xr,
                FFN_, DIM);
            ln2_proj<<<BcF, 256, 0, stream>>>(xr, g2, beta2, Ww, bw, out, chunk0);
        }
    }
}

// Round 3
// 960.279 us; speedup vs baseline: 1.3498x; 1.0949x over previous
//
#include <hip/hip_runtime.h>

#define B_SZ 16384
#define DIM  1024
#define NH   16
#define HD   64
#define FFN_ 4096

typedef __bf16 bf16x8 __attribute__((ext_vector_type(8)));
typedef unsigned short u16x8 __attribute__((ext_vector_type(8)));
typedef float f32x4 __attribute__((ext_vector_type(4)));

__device__ __forceinline__ unsigned short f2bf(float x) {
    union { float f; unsigned int u; } v; v.f = x;
    unsigned int r = v.u + 0x7FFFu + ((v.u >> 16) & 1u);
    return (unsigned short)(r >> 16);
}
__device__ __forceinline__ float bf2f(unsigned short u) {
    union { unsigned int u32; float f; } v; v.u32 = ((unsigned int)u) << 16;
    return v.f;
}

__device__ __forceinline__ void gload16(const void* g, void* lds) {
    __builtin_amdgcn_global_load_lds(
        (__attribute__((address_space(1))) void*)g,
        (__attribute__((address_space(3))) void*)lds,
        16, 0, 0);
}

// ---------------------------------------------------------------------------
// transpose + fp32->bf16 convert: W [K,N] fp32 -> WT [N,K] bf16
// ---------------------------------------------------------------------------
__global__ __launch_bounds__(256) void transpose_conv(
    const float* __restrict__ W, unsigned short* __restrict__ WT, int K, int N)
{
    __shared__ float tile[32][33];
    const int n0 = blockIdx.x * 32, k0 = blockIdx.y * 32;
    const int tx = threadIdx.x, ty = threadIdx.y;
    #pragma unroll
    for (int i = ty; i < 32; i += 8)
        tile[i][tx] = W[(size_t)(k0 + i) * N + n0 + tx];
    __syncthreads();
    #pragma unroll
    for (int i = ty; i < 32; i += 8)
        WT[(size_t)(n0 + i) * K + k0 + tx] = f2bf(tile[tx][i]);
}

__global__ __launch_bounds__(256) void concat_bias(
    const float* __restrict__ bk, const float* __restrict__ bv,
    float* __restrict__ bkv)
{
    int i = blockIdx.x * 256 + threadIdx.x;
    if (i < 1024) { bkv[i] = bk[i]; bkv[1024 + i] = bv[i]; }
}

// savg = bf16(mean(m0,m1,m2)); optionally also bf16 copies of m0,m1,m2
// (mjb = [3][B][DIM] bf16, j-major) for the bf16 KV GEMM path.
__global__ __launch_bounds__(256) void conv_inputs(
    const float4* __restrict__ m0, const float4* __restrict__ m1,
    const float4* __restrict__ m2, ushort4* __restrict__ savg,
    ushort4* __restrict__ mjb, int n4)
{
    int idx = blockIdx.x * blockDim.x + threadIdx.x;
    int stride = gridDim.x * blockDim.x;
    const float k = 1.f / 3.f;
    for (int i = idx; i < n4; i += stride) {
        float4 a = m0[i], b = m1[i], c = m2[i];
        ushort4 us;
        us.x = f2bf((a.x + b.x + c.x) * k); us.y = f2bf((a.y + b.y + c.y) * k);
        us.z = f2bf((a.z + b.z + c.z) * k); us.w = f2bf((a.w + b.w + c.w) * k);
        savg[i] = us;
        if (mjb) {
            ushort4 ua, ub, uc;
            ua.x = f2bf(a.x); ua.y = f2bf(a.y); ua.z = f2bf(a.z); ua.w = f2bf(a.w);
            ub.x = f2bf(b.x); ub.y = f2bf(b.y); ub.z = f2bf(b.z); ub.w = f2bf(b.w);
            uc.x = f2bf(c.x); uc.y = f2bf(c.y); uc.z = f2bf(c.z); uc.w = f2bf(c.w);
            mjb[i] = ua; mjb[n4 + i] = ub; mjb[2 * n4 + i] = uc;
        }
    }
}

// ---------------------------------------------------------------------------
// LEGACY 128x128 GEMM (kept for fallback tiers / AF32 KV path).
// ---------------------------------------------------------------------------
template <int MODE, bool AF32>
__global__ __launch_bounds__(256) void gemm2(
    const unsigned short* __restrict__ A,
    const float* __restrict__ A0, const float* __restrict__ A1,
    const float* __restrict__ A2, int chunk0, int Bc,
    const unsigned short* __restrict__ BT,
    const float* __restrict__ bias,
    const void* __restrict__ res,
    void* __restrict__ out, int K, int N)
{
    __shared__ __align__(16) char AsRaw[AF32 ? 32768 : 16384];
    __shared__ __align__(16) unsigned short Bs[2][4096];

    const int tid  = threadIdx.x;
    const int lane = tid & 63;
    const int wave = tid >> 6;
    const int wm = (wave >> 1) * 64;
    const int wn = (wave & 1) * 64;
    const int lr = lane & 15;
    const int quad = lane >> 4;

    const size_t rowB = (size_t)blockIdx.y * 128 + (tid >> 2);
    const int kcolB = (tid & 3) * 8;
    const unsigned short* Bg = BT + rowB * K + kcolB;

    const unsigned short* Ag = nullptr;
    const float* Agf = nullptr;
    if constexpr (AF32) {
        const int grow = blockIdx.x * 128;
        const int j = grow / Bc;
        const int b0 = (grow - j * Bc) + chunk0;
        const float* msrc = (j == 0) ? A0 : (j == 1) ? A1 : A2;
        const int arow = tid >> 3;
        const int jj = (tid & 7) ^ (arow & 7);
        Agf = msrc + (size_t)(b0 + arow) * DIM + jj * 4;
    } else {
        const size_t rowA = (size_t)blockIdx.x * 128 + (tid >> 2);
        Ag = A + rowA * K + kcolB;
    }

    f32x4 zero = {0.f, 0.f, 0.f, 0.f};
    f32x4 acc[4][4];
    #pragma unroll
    for (int i = 0; i < 4; ++i)
        #pragma unroll
        for (int j = 0; j < 4; ++j) acc[i][j] = zero;

    for (int k0 = 0; k0 < K; k0 += 64) {
        if constexpr (AF32) {
            float* Asf = (float*)AsRaw;
            #pragma unroll
            for (int h = 0; h < 2; ++h) {
                #pragma unroll
                for (int i = 0; i < 4; ++i)
                    gload16(Agf + (size_t)i * 32 * DIM + k0 + 32 * h,
                            (char*)(Asf + h * 4096) + i * 4096 + tid * 16);
            }
        } else {
            unsigned short* As = (unsigned short*)AsRaw;
            gload16(Ag + k0,                 (char*)As + tid * 16);
            gload16(Ag + (size_t)64 * K + k0,(char*)As + 4096 + tid * 16);
            gload16(Ag + k0 + 32,            (char*)As + 8192 + tid * 16);
            gload16(Ag + (size_t)64 * K + k0 + 32,
                                             (char*)As + 12288 + tid * 16);
        }
        gload16(Bg + k0,                  (char*)Bs[0] + tid * 16);
        gload16(Bg + (size_t)64 * K + k0, (char*)Bs[0] + 4096 + tid * 16);
        gload16(Bg + k0 + 32,             (char*)Bs[1] + tid * 16);
        gload16(Bg + (size_t)64 * K + k0 + 32,
                                          (char*)Bs[1] + 4096 + tid * 16);
        __syncthreads();

        #pragma unroll
        for (int h = 0; h < 2; ++h) {
            u16x8 af[4], bfr[4];
            if constexpr (AF32) {
                const float* Asf = (const float*)AsRaw + h * 4096;
                #pragma unroll
                for (int mi = 0; mi < 4; ++mi) {
                    const int r = wm + mi * 16 + lr;
                    const int s = lr & 7;
                    const float* rp = Asf + r * 32;
                    union { f32x4 f; unsigned int u[4]; } a0, a1;
                    a0.f = *(const f32x4*)(rp + (((quad << 1) ^ s) << 2));
                    a1.f = *(const f32x4*)(rp + ((((quad << 1) | 1) ^ s) << 2));
                    union { unsigned int i[4]; u16x8 v; } pk;
                    pk.i[0] = __builtin_amdgcn_perm(a0.u[1], a0.u[0], 0x07060302);
                    pk.i[1] = __builtin_amdgcn_perm(a0.u[3], a0.u[2], 0x07060302);
                    pk.i[2] = __builtin_amdgcn_perm(a1.u[1], a1.u[0], 0x07060302);
                    pk.i[3] = __builtin_amdgcn_perm(a1.u[3], a1.u[2], 0x07060302);
                    af[mi] = pk.v;
                }
            } else {
                const unsigned short* As =
                    (const unsigned short*)AsRaw + h * 4096;
                #pragma unroll
                for (int mi = 0; mi < 4; ++mi)
                    af[mi] = *(const u16x8*)&As[(wm + mi * 16 + lr) * 32 + quad * 8];
            }
            #pragma unroll
            for (int nj = 0; nj < 4; ++nj)
                bfr[nj] = *(const u16x8*)&Bs[h][(wn + nj * 16 + lr) * 32 + quad * 8];

            #pragma unroll
            for (int mi = 0; mi < 4; ++mi)
                #pragma unroll
                for (int nj = 0; nj < 4; ++nj)
                    acc[mi][nj] = __builtin_amdgcn_mfma_f32_16x16x32_bf16(
                        __builtin_bit_cast(bf16x8, af[mi]),
                        __builtin_bit_cast(bf16x8, bfr[nj]),
                        acc[mi][nj], 0, 0, 0);
        }
        __syncthreads();
    }

    const size_t rbase = (size_t)blockIdx.x * 128 + wm + quad * 4;
    const int cbase = blockIdx.y * 128 + wn + lr;
    #pragma unroll
    for (int mi = 0; mi < 4; ++mi) {
        #pragma unroll
        for (int nj = 0; nj < 4; ++nj) {
            const int gc = cbase + nj * 16;
            const float bv = bias[gc];
            #pragma unroll
            for (int r = 0; r < 4; ++r) {
                const size_t gr = rbase + mi * 16 + r;
                float v = acc[mi][nj][r] + bv;
                if (MODE == 1) v += ((const float*)res)[gr * N + gc];
                if (MODE == 2) v = v > 0.f ? v : 0.f;
                if (MODE == 4) {
                    v += bf2f(((const unsigned short*)res)[gr * N + gc]);
                    ((float*)out)[gr * N + gc] = v;
                } else {
                    ((unsigned short*)out)[gr * N + gc] = f2bf(v);
                }
            }
        }
    }
}

// ---------------------------------------------------------------------------
// 256x256x(BK=64) 8-wave pipelined GEMM: C[M,N] = A[M,K] @ BT[N,K]^T (+bias).
// 8 waves as 2(M)x4(N); per-wave output 2x(64 rows) x 2x(32 cols) via 4
// quadrant phases per K-tile. LDS: 2 double-buffers x (A 2x16KB + B 2x16KB)
// = 128 KiB dynamic. Staging via global_load_lds w/ counted vmcnt(4) per
// phase (never 0 in steady state); raw s_barrier; setprio(1) around MFMA.
// LDS XOR swizzle via pre-swizzled global source + swizzled ds_read addr.
// MODE 0: bf16 = acc+bias ; 1: bf16 = acc+bias+f32 res ; 2: bf16 relu ;
// 4: f32 = acc+bias+bf16 res.  CH: A rows = [3][B_SZ] j-major chunk mapping.
// ---------------------------------------------------------------------------
template <int MODE, bool CH>
__global__ __launch_bounds__(512, 2) void gemm256(
    const unsigned short* __restrict__ A, int chunk0, int Bc,
    const unsigned short* __restrict__ BT,
    const float* __restrict__ bias,
    const void* __restrict__ res,
    void* __restrict__ out, int K, int N)
{
    extern __shared__ __align__(16) char smem[];
    const int tid  = threadIdx.x;
    const int lane = tid & 63;
    const int wave = tid >> 6;
    const int wm = wave >> 2;       // 0..1
    const int wn = wave & 3;        // 0..3
    const int lr = lane & 15;
    const int quad = lane >> 4;

    const int srow  = tid >> 3;                           // 0..63 (+64 for i=1)
    const int scolb = ((tid & 7) ^ (srow & 7)) << 4;      // swizzled src col

    size_t arow0;
    if constexpr (CH) {
        const int grow = blockIdx.x * 256;
        const int j = grow / Bc;
        arow0 = (size_t)j * B_SZ + chunk0 + (grow - j * Bc);
    } else {
        arow0 = (size_t)blockIdx.x * 256;
    }
    const unsigned short* Ag = A + (arow0 + srow) * (size_t)K + (scolb >> 1);
    const unsigned short* Bg =
        BT + ((size_t)blockIdx.y * 256 + srow) * (size_t)K + (scolb >> 1);
    char* lds0 = smem + tid * 16;

    const int cbx0 = (quad * 16) ^ ((lr & 7) << 4);
    const int cbx1 = (64 + quad * 16) ^ ((lr & 7) << 4);

    f32x4 zero = {0.f, 0.f, 0.f, 0.f};
    f32x4 acc[2][2][4][2];
    #pragma unroll
    for (int a = 0; a < 2; ++a)
        #pragma unroll
        for (int b = 0; b < 2; ++b)
            #pragma unroll
            for (int c = 0; c < 4; ++c)
                #pragma unroll
                for (int d = 0; d < 2; ++d) acc[a][b][c][d] = zero;

    u16x8 af[4][2], bf0[2][2], bf1[2][2];

#define STAGE_A(nb, m, t) do {                                          \
        const unsigned short* s_ = Ag + (size_t)((m) * 128) * K + (t) * 64; \
        char* d_ = lds0 + (nb) * 65536 + (m) * 16384;                   \
        gload16(s_, d_);                                                \
        gload16(s_ + (size_t)64 * K, d_ + 8192); } while (0)
#define STAGE_B(nb, n, t) do {                                          \
        const unsigned short* s_ = Bg + (size_t)((n) * 128) * K + (t) * 64; \
        char* d_ = lds0 + (nb) * 65536 + 32768 + (n) * 16384;           \
        gload16(s_, d_);                                                \
        gload16(s_ + (size_t)64 * K, d_ + 8192); } while (0)
#define LOADA(nb, hm) do {                                              \
        const char* b_ = smem + (nb) * 65536 + (hm) * 16384;            \
        _Pragma("unroll")                                               \
        for (int mi = 0; mi < 4; ++mi) {                                \
            const int ar_ = wm * 64 + mi * 16 + lr;                     \
            af[mi][0] = *(const u16x8*)(b_ + ar_ * 128 + cbx0);         \
            af[mi][1] = *(const u16x8*)(b_ + ar_ * 128 + cbx1); } } while (0)
#define LOADB(nb, hn, dst) do {                                         \
        const char* b_ = smem + (nb) * 65536 + 32768 + (hn) * 16384;    \
        _Pragma("unroll")                                               \
        for (int nj = 0; nj < 2; ++nj) {                                \
            const int br_ = wn * 32 + nj * 16 + lr;                     \
            dst[nj][0] = *(const u16x8*)(b_ + br_ * 128 + cbx0);        \
            dst[nj][1] = *(const u16x8*)(b_ + br_ * 128 + cbx1); } } while (0)
#define MFMAQ(QM, QN, BF)                                               \
        _Pragma("unroll")                                               \
        for (int mi = 0; mi < 4; ++mi)                                  \
        _Pragma("unroll")                                               \
        for (int nj = 0; nj < 2; ++nj)                                  \
        _Pragma("unroll")                                               \
        for (int ks = 0; ks < 2; ++ks)                                  \
            acc[QM][QN][mi][nj] = __builtin_amdgcn_mfma_f32_16x16x32_bf16( \
                __builtin_bit_cast(bf16x8, af[mi][ks]),                 \
                __builtin_bit_cast(bf16x8, BF[nj][ks]),                 \
                acc[QM][QN][mi][nj], 0, 0, 0);

    const int NT = K >> 6;
    STAGE_A(0, 0, 0); STAGE_B(0, 0, 0); STAGE_B(0, 1, 0); STAGE_A(0, 1, 0);
    asm volatile("s_waitcnt vmcnt(4)" ::: "memory");
    __builtin_amdgcn_s_barrier();

    for (int t = 0; t < NT; ++t) {
        const int nb = t & 1, ob = nb ^ 1;
        const bool more = (t + 1) < NT;
        // phase 0: quadrant (0,0)
        LOADA(nb, 0); LOADB(nb, 0, bf0);
        if (more) { STAGE_A(ob, 0, t + 1);
                    asm volatile("s_waitcnt vmcnt(4)" ::: "memory"); }
        else      { asm volatile("s_waitcnt vmcnt(2)" ::: "memory"); }
        __builtin_amdgcn_s_barrier();
        __builtin_amdgcn_s_setprio(1);
        MFMAQ(0, 0, bf0);
        __builtin_amdgcn_s_setprio(0);
        __builtin_amdgcn_s_barrier();
        // phase 1: quadrant (0,1)
        LOADB(nb, 1, bf1);
        if (more) { STAGE_B(ob, 0, t + 1);
                    asm volatile("s_waitcnt vmcnt(4)" ::: "memory"); }
        else      { asm volatile("s_waitcnt vmcnt(0)" ::: "memory"); }
        __builtin_amdgcn_s_barrier();
        __builtin_amdgcn_s_setprio(1);
        MFMAQ(0, 1, bf1);
        __builtin_amdgcn_s_setprio(0);
        __builtin_amdgcn_s_barrier();
        // phase 2: quadrant (1,1)
        LOADA(nb, 1);
        if (more) { STAGE_B(ob, 1, t + 1);
                    asm volatile("s_waitcnt vmcnt(4)" ::: "memory"); }
        __builtin_amdgcn_s_barrier();
        __builtin_amdgcn_s_setprio(1);
        MFMAQ(1, 1, bf1);
        __builtin_amdgcn_s_setprio(0);
        __builtin_amdgcn_s_barrier();
        // phase 3: quadrant (1,0)  (bf0 still live from phase 0)
        if (more) { STAGE_A(ob, 1, t + 1);
                    asm volatile("s_waitcnt vmcnt(4)" ::: "memory"); }
        __builtin_amdgcn_s_barrier();
        __builtin_amdgcn_s_setprio(1);
        MFMAQ(1, 0, bf0);
        __builtin_amdgcn_s_setprio(0);
        __builtin_amdgcn_s_barrier();
    }

#undef STAGE_A
#undef STAGE_B
#undef LOADA
#undef LOADB
#undef MFMAQ

    // epilogue: C/D layout col = lane&15, row = quad*4 + reg
    #pragma unroll
    for (int qm = 0; qm < 2; ++qm) {
        #pragma unroll
        for (int qn = 0; qn < 2; ++qn) {
            #pragma unroll
            for (int mi = 0; mi < 4; ++mi) {
                #pragma unroll
                for (int nj = 0; nj < 2; ++nj) {
                    const size_t gr0 = (size_t)blockIdx.x * 256 + qm * 128 +
                                       wm * 64 + mi * 16 + quad * 4;
                    const int gc = blockIdx.y * 256 + qn * 128 + wn * 32 +
                                   nj * 16 + lr;
                    const float bv = bias[gc];
                    f32x4 av = acc[qm][qn][mi][nj];
                    #pragma unroll
                    for (int r = 0; r < 4; ++r) {
                        const size_t gr = gr0 + r;
                        float v = av[r] + bv;
                        if (MODE == 1) v += ((const float*)res)[gr * N + gc];
                        if (MODE == 2) v = v > 0.f ? v : 0.f;
                        if (MODE == 4) {
                            v += bf2f(((const unsigned short*)res)[gr * N + gc]);
                            ((float*)out)[gr * N + gc] = v;
                        } else {
                            ((unsigned short*)out)[gr * N + gc] = f2bf(v);
                        }
                    }
                }
            }
        }
    }
}

// ---------------------------------------------------------------------------
// attention (3 keys) + residual + LN1.  One row per block, 256 threads.
// ---------------------------------------------------------------------------
__global__ __launch_bounds__(256) void attn_ln1(
    const unsigned short* __restrict__ qb,
    const unsigned short* __restrict__ KVb,
    const float* __restrict__ domain,
    const float* __restrict__ g1, const float* __restrict__ beta1,
    unsigned short* __restrict__ x1b, int chunk0, int Bc)
{
    const int b = blockIdx.x;
    const int t = threadIdx.x;
    const int d0 = t * 4;
    const size_t gbase = (size_t)(chunk0 + b) * DIM + d0;

    float q[4];
    { ushort4 u = *(const ushort4*)(qb + gbase);
      q[0] = bf2f(u.x); q[1] = bf2f(u.y); q[2] = bf2f(u.z); q[3] = bf2f(u.w); }

    float vv[3][4], s[3];
    #pragma unroll
    for (int j = 0; j < 3; ++j) {
        const size_t off = ((size_t)j * Bc + b) * 2048 + d0;
        ushort4 ku = *(const ushort4*)(KVb + off);
        ushort4 vu = *(const ushort4*)(KVb + off + 1024);
        float p = q[0] * bf2f(ku.x) + q[1] * bf2f(ku.y) +
                  q[2] * bf2f(ku.z) + q[3] * bf2f(ku.w);
        vv[j][0] = bf2f(vu.x); vv[j][1] = bf2f(vu.y);
        vv[j][2] = bf2f(vu.z); vv[j][3] = bf2f(vu.w);
        p += __shfl_down(p, 8, 16);
        p += __shfl_down(p, 4, 16);
        p += __shfl_down(p, 2, 16);
        p += __shfl_down(p, 1, 16);
        p = __shfl(p, 0, 16);
        s[j] = p * 0.125f;
    }
    float mx = fmaxf(s[0], fmaxf(s[1], s[2]));
    float e0 = __expf(s[0] - mx), e1 = __expf(s[1] - mx), e2 = __expf(s[2] - mx);
    float inv = 1.f / (e0 + e1 + e2);
    float a0 = e0 * inv, a1 = e1 * inv, a2 = e2 * inv;

    float4 dm = *(const float4*)(domain + gbase);
    float y[4];
    y[0] = dm.x + a0 * vv[0][0] + a1 * vv[1][0] + a2 * vv[2][0];
    y[1] = dm.y + a0 * vv[0][1] + a1 * vv[1][1] + a2 * vv[2][1];
    y[2] = dm.z + a0 * vv[0][2] + a1 * vv[1][2] + a2 * vv[2][2];
    y[3] = dm.w + a0 * vv[0][3] + a1 * vv[1][3] + a2 * vv[2][3];

    float sum = y[0] + y[1] + y[2] + y[3];
    float sq  = y[0]*y[0] + y[1]*y[1] + y[2]*y[2] + y[3]*y[3];
    #pragma unroll
    for (int off = 32; off > 0; off >>= 1) {
        sum += __shfl_down(sum, off, 64);
        sq  += __shfl_down(sq,  off, 64);
    }
    __shared__ float red[8];
    const int wv = t >> 6, ln = t & 63;
    if (ln == 0) { red[wv] = sum; red[4 + wv] = sq; }
    __syncthreads();
    float tot = red[0] + red[1] + red[2] + red[3];
    float tsq = red[4] + red[5] + red[6] + red[7];
    float mu = tot * (1.f / DIM);
    float var = tsq * (1.f / DIM) - mu * mu;
    float rs = rsqrtf(var + 1e-5f);
    #pragma unroll
    for (int i = 0; i < 4; ++i) {
        int d = d0 + i;
        float xv = (y[i] - mu) * rs * g1[d] + beta1[d];
        x1b[gbase + i] = f2bf(xv);
    }
}

// ---------------------------------------------------------------------------
// LN2 + [DIM,3] projection + softmax.  One row per block, 256 threads.
// ---------------------------------------------------------------------------
__global__ __launch_bounds__(256) void ln2_proj(
    const float* __restrict__ xr,
    const float* __restrict__ g2, const float* __restrict__ beta2,
    const float* __restrict__ Ww, const float* __restrict__ bw,
    float* __restrict__ out, int chunk0)
{
    const int b = blockIdx.x;
    const int t = threadIdx.x;
    const int d0 = t * 4;
    const size_t base = (size_t)b * DIM + d0;
    float4 x = *(const float4*)(xr + base);
    float xs[4] = {x.x, x.y, x.z, x.w};

    float sum = xs[0] + xs[1] + xs[2] + xs[3];
    float sq  = xs[0]*xs[0] + xs[1]*xs[1] + xs[2]*xs[2] + xs[3]*xs[3];
    #pragma unroll
    for (int off = 32; off > 0; off >>= 1) {
        sum += __shfl_down(sum, off, 64);
        sq  += __shfl_down(sq,  off, 64);
    }
    __shared__ float red[8];
    const int wv = t >> 6, ln = t & 63;
    if (ln == 0) { red[wv] = sum; red[4 + wv] = sq; }
    __syncthreads();
    float tot = red[0] + red[1] + red[2] + red[3];
    float tsq = red[4] + red[5] + red[6] + red[7];
    float mu = tot * (1.f / DIM);
    float var = tsq * (1.f / DIM) - mu * mu;
    float rs = rsqrtf(var + 1e-5f);

    float p0 = 0.f, p1 = 0.f, p2 = 0.f;
    #pragma unroll
    for (int i = 0; i < 4; ++i) {
        int d = d0 + i;
        float xv = (xs[i] - mu) * rs * g2[d] + beta2[d];
        p0 += xv * Ww[d * 3 + 0];
        p1 += xv * Ww[d * 3 + 1];
        p2 += xv * Ww[d * 3 + 2];
    }
    #pragma unroll
    for (int off = 32; off > 0; off >>= 1) {
        p0 += __shfl_down(p0, off, 64);
        p1 += __shfl_down(p1, off, 64);
        p2 += __shfl_down(p2, off, 64);
    }
    __shared__ float pr[12];
    if (ln == 0) { pr[wv] = p0; pr[4 + wv] = p1; pr[8 + wv] = p2; }
    __syncthreads();
    if (t == 0) {
        float l0 = pr[0] + pr[1] + pr[2] + pr[3] + bw[0];
        float l1 = pr[4] + pr[5] + pr[6] + pr[7] + bw[1];
        float l2 = pr[8] + pr[9] + pr[10] + pr[11] + bw[2];
        float m = fmaxf(l0, fmaxf(l1, l2));
        float e0 = __expf(l0 - m), e1 = __expf(l1 - m), e2 = __expf(l2 - m);
        float inv = 1.f / (e0 + e1 + e2);
        out[(size_t)(chunk0 + b) * 3 + 0] = e0 * inv;
        out[(size_t)(chunk0 + b) * 3 + 1] = e1 * inv;
        out[(size_t)(chunk0 + b) * 3 + 2] = e2 * inv;
    }
}

// ---------------------------------------------------------------------------
extern "C" void kernel_launch(void* const* d_in, const int* in_sizes, int n_in,
                              void* d_out, int out_size, void* d_ws, size_t ws_size,
                              hipStream_t stream)
{
    const float* m0     = (const float*)d_in[0];
    const float* m1     = (const float*)d_in[1];
    const float* m2     = (const float*)d_in[2];
    const float* domain = (const float*)d_in[3];
    const float* Wg = (const float*)d_in[4];  const float* bg = (const float*)d_in[5];
    const float* Wq = (const float*)d_in[6];  const float* bq = (const float*)d_in[7];
    const float* Wk = (const float*)d_in[8];  const float* bk = (const float*)d_in[9];
    const float* Wv = (const float*)d_in[10]; const float* bv = (const float*)d_in[11];
    const float* W1 = (const float*)d_in[12]; const float* b1 = (const float*)d_in[13];
    const float* W2 = (const float*)d_in[14]; const float* b2 = (const float*)d_in[15];
    const float* g1 = (const float*)d_in[16]; const float* beta1 = (const float*)d_in[17];
    const float* g2 = (const float*)d_in[18]; const float* beta2 = (const float*)d_in[19];
    const float* Ww = (const float*)d_in[20]; const float* bw = (const float*)d_in[21];
    float* out = (float*)d_out;

    char* ws = (char*)d_ws;
    const size_t MiB = 1ull << 20;

    // one-time: raise dynamic-LDS cap for gemm256 instantiations (128 KiB)
    static int attr_ok = -1;
    if (attr_ok < 0) {
        hipError_t e = hipFuncSetAttribute(
            reinterpret_cast<const void*>(&gemm256<0, false>),
            hipFuncAttributeMaxDynamicSharedMemorySize, 131072);
        if (e == hipSuccess) e = hipFuncSetAttribute(
            reinterpret_cast<const void*>(&gemm256<0, true>),
            hipFuncAttributeMaxDynamicSharedMemorySize, 131072);
        if (e == hipSuccess) e = hipFuncSetAttribute(
            reinterpret_cast<const void*>(&gemm256<1, false>),
            hipFuncAttributeMaxDynamicSharedMemorySize, 131072);
        if (e == hipSuccess) e = hipFuncSetAttribute(
            reinterpret_cast<const void*>(&gemm256<2, false>),
            hipFuncAttributeMaxDynamicSharedMemorySize, 131072);
        if (e == hipSuccess) e = hipFuncSetAttribute(
            reinterpret_cast<const void*>(&gemm256<4, false>),
            hipFuncAttributeMaxDynamicSharedMemorySize, 131072);
        attr_ok = (e == hipSuccess) ? 1 : 0;
    }

    unsigned short* wgT  = (unsigned short*)(ws);
    unsigned short* wqT  = (unsigned short*)(ws + 2 * MiB);
    unsigned short* wkvT = (unsigned short*)(ws + 4 * MiB);   // [2048,1024]
    unsigned short* w1T  = (unsigned short*)(ws + 8 * MiB);
    unsigned short* w2T  = (unsigned short*)(ws + 16 * MiB);
    float*          bkv  = (float*)(ws + 24 * MiB);

    const dim3 tb(32, 8);
    transpose_conv<<<dim3(DIM / 32, DIM / 32), tb, 0, stream>>>(Wg, wgT, DIM, DIM);
    transpose_conv<<<dim3(DIM / 32, DIM / 32), tb, 0, stream>>>(Wq, wqT, DIM, DIM);
    transpose_conv<<<dim3(DIM / 32, DIM / 32), tb, 0, stream>>>(Wk, wkvT, DIM, DIM);
    transpose_conv<<<dim3(DIM / 32, DIM / 32), tb, 0, stream>>>(
        Wv, wkvT + (size_t)DIM * DIM, DIM, DIM);
    transpose_conv<<<dim3(FFN_ / 32, DIM / 32), tb, 0, stream>>>(W1, w1T, DIM, FFN_);
    transpose_conv<<<dim3(DIM / 32, FFN_ / 32), tb, 0, stream>>>(W2, w2T, FFN_, DIM);
    concat_bias<<<4, 256, 0, stream>>>(bk, bv, bkv);

    char* base = ws + 25 * MiB;
    const int n4 = B_SZ * DIM / 4;

    if (attr_ok) {
        const bool FULLT = ws_size >= 282 * MiB;
        const bool MIDT  = !FULLT && ws_size >= 250 * MiB;
        if (FULLT || MIDT) {
            // layout (all offsets from base):
            //   KV phase: mjb [0,96) | qb [96,128) | x1b [128,160) |
            //             shared [160,..): savg(32)+dq(32) then KVb per chunk
            //   FFN phase: h1 [0,128) over dead mjb+qb | x1b live |
            //              xr at shared (64 MiB) over dead KVb
            const int BcKV = FULLT ? 8192 : 4096;
            unsigned short* mjb  = (unsigned short*)(base);
            unsigned short* qb   = (unsigned short*)(base + 96 * MiB);
            unsigned short* x1b  = (unsigned short*)(base + 128 * MiB);
            char* shared         = base + 160 * MiB;
            unsigned short* savg = (unsigned short*)(shared);
            unsigned short* dq   = (unsigned short*)(shared + 32 * MiB);
            unsigned short* KVb  = (unsigned short*)(shared);
            unsigned short* h1   = (unsigned short*)(base);     // 128 MiB
            float*          xr   = (float*)(shared);            // 64 MiB

            conv_inputs<<<8192, 256, 0, stream>>>(
                (const float4*)m0, (const float4*)m1, (const float4*)m2,
                (ushort4*)savg, (ushort4*)mjb, n4);

            gemm256<1, false><<<dim3(B_SZ / 256, DIM / 256), 512, 131072, stream>>>(
                savg, 0, 0, wgT, bg, domain, dq, DIM, DIM);
            gemm256<0, false><<<dim3(B_SZ / 256, DIM / 256), 512, 131072, stream>>>(
                dq, 0, 0, wqT, bq, nullptr, qb, DIM, DIM);

            for (int c = 0; c < B_SZ / BcKV; ++c) {
                const int chunk0 = c * BcKV;
                gemm256<0, true><<<dim3(3 * BcKV / 256, 2048 / 256), 512, 131072, stream>>>(
                    mjb, chunk0, BcKV, wkvT, bkv, nullptr, KVb, DIM, 2048);
                attn_ln1<<<BcKV, 256, 0, stream>>>(qb, KVb, domain, g1, beta1,
                                                   x1b, chunk0, BcKV);
            }

            // full-B FFN: FFN2 grid = (64,4) = 256 blocks = 1 block/CU
            gemm256<2, false><<<dim3(B_SZ / 256, FFN_ / 256), 512, 131072, stream>>>(
                x1b, 0, 0, w1T, b1, nullptr, h1, DIM, FFN_);
            gemm256<4, false><<<dim3(B_SZ / 256, DIM / 256), 512, 131072, stream>>>(
                h1, 0, 0, w2T, b2, x1b, xr, FFN_, DIM);
            ln2_proj<<<B_SZ, 256, 0, stream>>>(xr, g2, beta2, Ww, bw, out, 0);
            return;
        }
        // fallback-KV tier: gemm256 for dq/qb/FFN, legacy AF32 gemm2 for KV
        const bool T2 = ws_size >= 185 * MiB;
        const int BcKV = T2 ? 8192 : 4096;
        const int BcF  = T2 ? 8192 : 4096;
        unsigned short* savg = (unsigned short*)(base);
        unsigned short* qb   = (unsigned short*)(base);
        unsigned short* x1b  = (unsigned short*)(base + 32 * MiB);
        unsigned short* dq   = (unsigned short*)(base + 64 * MiB);
        unsigned short* KVb  = (unsigned short*)(base + 64 * MiB);
        unsigned short* h1   = (unsigned short*)(base + 64 * MiB);
        float*          xr   = (float*)(base + 64 * MiB + (size_t)BcF * FFN_ * 2);

        conv_inputs<<<8192, 256, 0, stream>>>(
            (const float4*)m0, (const float4*)m1, (const float4*)m2,
            (ushort4*)savg, nullptr, n4);

        gemm256<1, false><<<dim3(B_SZ / 256, DIM / 256), 512, 131072, stream>>>(
            savg, 0, 0, wgT, bg, domain, dq, DIM, DIM);
        gemm256<0, false><<<dim3(B_SZ / 256, DIM / 256), 512, 131072, stream>>>(
            dq, 0, 0, wqT, bq, nullptr, qb, DIM, DIM);

        for (int c = 0; c < B_SZ / BcKV; ++c) {
            const int chunk0 = c * BcKV;
            gemm2<0, true><<<dim3(3 * BcKV / 128, 2048 / 128), 256, 0, stream>>>(
                nullptr, m0, m1, m2, chunk0, BcKV, wkvT, bkv, nullptr, KVb,
                DIM, 2048);
            attn_ln1<<<BcKV, 256, 0, stream>>>(qb, KVb, domain, g1, beta1,
                                               x1b, chunk0, BcKV);
        }
        for (int c = 0; c < B_SZ / BcF; ++c) {
            const int chunk0 = c * BcF;
            const unsigned short* x1c = x1b + (size_t)chunk0 * DIM;
            gemm256<2, false><<<dim3(BcF / 256, FFN_ / 256), 512, 131072, stream>>>(
                x1c, 0, 0, w1T, b1, nullptr, h1, DIM, FFN_);
            gemm256<4, false><<<dim3(BcF / 256, DIM / 256), 512, 131072, stream>>>(
                h1, 0, 0, w2T, b2, x1c, xr, FFN_, DIM);
            ln2_proj<<<BcF, 256, 0, stream>>>(xr, g2, beta2, Ww, bw, out, chunk0);
        }
        return;
    }

    // full legacy path (attribute raise failed): original kernel set
    {
        const bool T2 = ws_size >= 185 * MiB;
        const int BcKV = T2 ? 8192 : 4096;
        const int BcF  = T2 ? 8192 : 4096;
        unsigned short* savg = (unsigned short*)(base);
        unsigned short* qb   = (unsigned short*)(base);
        unsigned short* x1b  = (unsigned short*)(base + 32 * MiB);
        unsigned short* dq   = (unsigned short*)(base + 64 * MiB);
        unsigned short* KVb  = (unsigned short*)(base + 64 * MiB);
        unsigned short* h1   = (unsigned short*)(base + 64 * MiB);
        float*          xr   = (float*)(base + 64 * MiB + (size_t)BcF * FFN_ * 2);

        conv_inputs<<<8192, 256, 0, stream>>>(
            (const float4*)m0, (const float4*)m1, (const float4*)m2,
            (ushort4*)savg, nullptr, n4);

        gemm2<1, false><<<dim3(B_SZ / 128, DIM / 128), 256, 0, stream>>>(
            savg, nullptr, nullptr, nullptr, 0, 0, wgT, bg, domain, dq, DIM, DIM);
        gemm2<0, false><<<dim3(B_SZ / 128, DIM / 128), 256, 0, stream>>>(
            dq, nullptr, nullptr, nullptr, 0, 0, wqT, bq, nullptr, qb, DIM, DIM);

        for (int c = 0; c < B_SZ / BcKV; ++c) {
            const int chunk0 = c * BcKV;
            gemm2<0, true><<<dim3(3 * BcKV / 128, 2048 / 128), 256, 0, stream>>>(
                nullptr, m0, m1, m2, chunk0, BcKV, wkvT, bkv, nullptr, KVb,
                DIM, 2048);
            attn_ln1<<<BcKV, 256, 0, stream>>>(qb, KVb, domain, g1, beta1,
                                               x1b, chunk0, BcKV);
        }
        for (int c = 0; c < B_SZ / BcF; ++c) {
            const int chunk0 = c * BcF;
            const unsigned short* x1c = x1b + (size_t)chunk0 * DIM;
            gemm2<2, false><<<dim3(BcF / 128, FFN_ / 128), 256, 0, stream>>>(
                x1c, nullptr, nullptr, nullptr, 0, 0, w1T, b1, nullptr, h1,
                DIM, FFN_);
            gemm2<4, false><<<dim3(BcF / 128, DIM / 128), 256, 0, stream>>>(
                h1, nullptr, nullptr, nullptr, 0, 0, w2T, b2, x1c, xr,
                FFN_, DIM);
            ln2_proj<<<BcF, 256, 0, stream>>>(xr, g2, beta2, Ww, bw, out, chunk0);
        }
    }
}